// Round 12
// baseline (669.364 us; speedup 1.0000x reference)
//
#include <hip/hip_runtime.h>

#define DECAY 0.8f
#define EPS   1e-5f
#define HN    8
#define BB    8
#define NSEQ  2048
#define DD    64
#define CC    1024
#define NROW  (BB*NSEQ)   /* 16384 rows per head */
#define TAU   0.02f       /* margin threshold; split err bound ~1e-4 -> 100x safety */

typedef _Float16 f16x8 __attribute__((ext_vector_type(8)));
typedef float    f32x4 __attribute__((ext_vector_type(4)));
typedef float    vf4   __attribute__((ext_vector_type(4)));

#define MFMA16(a,b,c) __builtin_amdgcn_mfma_f32_16x16x32_f16(a, b, c, 0, 0, 0)

#define GLL16(gsrc, ldst) \
  __builtin_amdgcn_global_load_lds((const __attribute__((address_space(1))) void*)(gsrc), \
                                   (__attribute__((address_space(3))) void*)(ldst), 16, 0, 0)

// ---------------- kernel 1: row sum-of-squares for x and embed ----------------
__global__ void sumsq_kernel(const float* __restrict__ x, const float* __restrict__ embed,
                             float* __restrict__ fsq, float* __restrict__ esq) {
    int tid = blockIdx.x * blockDim.x + threadIdx.x;
    const int totalF = HN * NROW;
    const int totalE = HN * CC;
    if (tid < totalF) {
        const float4* src = (const float4*)(x + (size_t)tid * DD);
        float s = 0.f;
        #pragma unroll
        for (int i = 0; i < DD/4; ++i) {
            float4 v = src[i];
            s = fmaf(v.x, v.x, s); s = fmaf(v.y, v.y, s);
            s = fmaf(v.z, v.z, s); s = fmaf(v.w, v.w, s);
        }
        fsq[tid] = s;
    } else if (tid < totalF + totalE) {
        int t = tid - totalF;
        const float4* src = (const float4*)(embed + (size_t)t * DD);
        float s = 0.f;
        #pragma unroll
        for (int i = 0; i < DD/4; ++i) {
            float4 v = src[i];
            s = fmaf(v.x, v.x, s); s = fmaf(v.y, v.y, s);
            s = fmaf(v.z, v.z, s); s = fmaf(v.w, v.w, s);
        }
        esq[t] = s;
    }
}

// swizzled byte offset for [col][k] f16 plane (row stride 128 B)
__device__ __forceinline__ int lds_off(int col, int k) {
    return (col * 128 + k * 2) ^ ((col & 7) << 4);
}

// ---------------- kernel 1b: pre-split embed into swizzled f16 hi/lo planes ----------------
__global__ __launch_bounds__(256)
void presplit_kernel(const float* __restrict__ embed, _Float16* __restrict__ esplit) {
    const int t    = blockIdx.x * 256 + threadIdx.x;   // 65536 threads
    const int kg   = (t & 7) * 8;                      // k group of 8
    const int code = t >> 3;                           // h*1024 + c
    const int h    = code >> 10;
    const int c    = code & 1023;
    const int chunk = c >> 7;
    const int col   = c & 127;

    const float* s = embed + (size_t)code * DD + kg;
    float4 v0 = *(const float4*)s;
    float4 v1 = *(const float4*)(s + 4);
    float f0 = v0.x, f1 = v0.y, f2 = v0.z, f3 = v0.w;
    float f4 = v1.x, f5 = v1.y, f6 = v1.z, f7 = v1.w;

    f16x8 hi, lo;
    hi[0] = (_Float16)f0; lo[0] = (_Float16)(f0 - (float)hi[0]);
    hi[1] = (_Float16)f1; lo[1] = (_Float16)(f1 - (float)hi[1]);
    hi[2] = (_Float16)f2; lo[2] = (_Float16)(f2 - (float)hi[2]);
    hi[3] = (_Float16)f3; lo[3] = (_Float16)(f3 - (float)hi[3]);
    hi[4] = (_Float16)f4; lo[4] = (_Float16)(f4 - (float)hi[4]);
    hi[5] = (_Float16)f5; lo[5] = (_Float16)(f5 - (float)hi[5]);
    hi[6] = (_Float16)f6; lo[6] = (_Float16)(f6 - (float)hi[6]);
    hi[7] = (_Float16)f7; lo[7] = (_Float16)(f7 - (float)hi[7]);

    char* base = (char*)esplit + ((size_t)(h*8 + chunk)) * 32768;
    const int off = lds_off(col, kg);
    *(f16x8*)(base + off)         = hi;
    *(f16x8*)(base + 16384 + off) = lo;
}

// ------------- kernel 2: MFMA (E as A-operand) dist + argmax + margin + q/oh/dist -------------
__global__ __launch_bounds__(256, 2)
void dist_mfma_kernel(const float* __restrict__ x, const _Float16* __restrict__ esplit,
                      const float* __restrict__ embed,
                      const float* __restrict__ fsq, const float* __restrict__ esq,
                      float* __restrict__ out_i, float* __restrict__ margin,
                      float* __restrict__ out_q, float* __restrict__ out_oh,
                      float* __restrict__ out_d) {
    __shared__ _Float16 eb[2][16384];   // [buf][hi 8192 | lo 8192], 64 KiB

    const int h   = blockIdx.y;
    const int n0  = blockIdx.x * 128;
    const int tid = threadIdx.x;
    const int wv  = tid >> 6;       // wave 0..3 -> x rows wv*32..wv*32+31
    const int l   = tid & 63;
    const int l15 = l & 15;         // x-row within 16
    const int l4  = l >> 4;         // code sub-group

    const float* xh_   = x     + (size_t)h * NROW * DD;
    const float* eh_   = embed + (size_t)h * CC   * DD;
    const float* esq_h = esq   + h * CC;
    const _Float16* es_h = esplit + (size_t)h * 8 * 16384;

    // ---- stage chunk 0 into buf 0 (async DMA) ----
    #pragma unroll
    for (int i = 0; i < 8; ++i) {
        const int o = (i*4 + wv) * 512;              // f16 offset, wave-uniform
        GLL16(es_h + o + l*8, &eb[0][o]);
    }

    // ---- X fragments (B operand): x-row = n0+wv*32+rt*16+l15, k = ks*32+l4*8+j ----
    f16x8 Xh[2][2], Xl[2][2];
    #pragma unroll
    for (int rt = 0; rt < 2; ++rt)
        #pragma unroll
        for (int ks = 0; ks < 2; ++ks) {
            const float* src = xh_ + (size_t)(n0 + wv*32 + rt*16 + l15) * DD + ks*32 + l4*8;
            float4 v0 = *(const float4*)src;
            float4 v1 = *(const float4*)(src + 4);
            f16x8 hh, ll;
            hh[0] = (_Float16)v0.x; ll[0] = (_Float16)(v0.x - (float)hh[0]);
            hh[1] = (_Float16)v0.y; ll[1] = (_Float16)(v0.y - (float)hh[1]);
            hh[2] = (_Float16)v0.z; ll[2] = (_Float16)(v0.z - (float)hh[2]);
            hh[3] = (_Float16)v0.w; ll[3] = (_Float16)(v0.w - (float)hh[3]);
            hh[4] = (_Float16)v1.x; ll[4] = (_Float16)(v1.x - (float)hh[4]);
            hh[5] = (_Float16)v1.y; ll[5] = (_Float16)(v1.y - (float)hh[5]);
            hh[6] = (_Float16)v1.z; ll[6] = (_Float16)(v1.z - (float)hh[6]);
            hh[7] = (_Float16)v1.w; ll[7] = (_Float16)(v1.w - (float)hh[7]);
            Xh[rt][ks] = hh; Xl[rt][ks] = ll;
        }

    float fs[2];
    #pragma unroll
    for (int rt = 0; rt < 2; ++rt)
        fs[rt] = fsq[h*NROW + n0 + wv*32 + rt*16 + l15];

    asm volatile("s_waitcnt vmcnt(0)" ::: "memory");
    __builtin_amdgcn_s_barrier();
    asm volatile("" ::: "memory");

    float best1[2], best2[2];
    int   bid[2];
    #pragma unroll
    for (int rt = 0; rt < 2; ++rt) { best1[rt] = -3.4e38f; best2[rt] = -3.4e38f; bid[rt] = 0; }

    #pragma unroll 1
    for (int ci = 0; ci < 8; ++ci) {
        const int c0 = ci * 128;
        const int b  = ci & 1;

        // issue next chunk's DMA first (oldest in vmcnt queue)
        if (ci < 7) {
            const _Float16* src = es_h + (size_t)(ci + 1) * 16384;
            #pragma unroll
            for (int i = 0; i < 8; ++i) {
                const int o = (i*4 + wv) * 512;
                GLL16(src + o + l*8, &eb[b^1][o]);
            }
        }

        const _Float16* ph = &eb[b][0];
        const _Float16* pl = &eb[b][8192];

        #pragma unroll
        for (int ct = 0; ct < 8; ++ct) {
            const int col = ct*16 + l15;   // embed code for this lane's A-frag
            f16x8 Eh0 = *(const f16x8*)((const char*)ph + lds_off(col, 0  + l4*8));
            f16x8 Eh1 = *(const f16x8*)((const char*)ph + lds_off(col, 32 + l4*8));
            f16x8 El0 = *(const f16x8*)((const char*)pl + lds_off(col, 0  + l4*8));
            f16x8 El1 = *(const f16x8*)((const char*)pl + lds_off(col, 32 + l4*8));

            f32x4 a0 = {0.f, 0.f, 0.f, 0.f};
            f32x4 a1 = {0.f, 0.f, 0.f, 0.f};
            a0 = MFMA16(Eh0, Xh[0][0], a0); a1 = MFMA16(Eh0, Xh[1][0], a1);
            a0 = MFMA16(Eh1, Xh[0][1], a0); a1 = MFMA16(Eh1, Xh[1][1], a1);
            a0 = MFMA16(Eh0, Xl[0][0], a0); a1 = MFMA16(Eh0, Xl[1][0], a1);
            a0 = MFMA16(Eh1, Xl[0][1], a0); a1 = MFMA16(Eh1, Xl[1][1], a1);
            a0 = MFMA16(El0, Xh[0][0], a0); a1 = MFMA16(El0, Xh[1][0], a1);
            a0 = MFMA16(El1, Xh[0][1], a0); a1 = MFMA16(El1, Xh[1][1], a1);

            const int c_base = c0 + ct*16 + l4*4;   // 4 consecutive codes
            float eq[4];
            *(float4*)&eq[0] = *(const float4*)(esq_h + c_base);

            #pragma unroll
            for (int rt = 0; rt < 2; ++rt) {
                const f32x4 acc = rt ? a1 : a0;
                const int   row = n0 + wv*32 + rt*16 + l15;
                float dv[4];
                #pragma unroll
                for (int j = 0; j < 4; ++j)
                    dv[j] = fmaf(2.f, acc[j], -(fs[rt] + eq[j]));

                vf4 d4 = {dv[0], dv[1], dv[2], dv[3]};
                *(vf4*)(out_d + ((size_t)h*NROW + row)*CC + c_base) = d4;  // plain: L2 write-combine

                #pragma unroll
                for (int j = 0; j < 4; ++j) {
                    // branchless top-2 insert
                    float nb2 = fmaxf(best2[rt], fminf(dv[j], best1[rt]));
                    bool  gt  = dv[j] > best1[rt];
                    best1[rt] = fmaxf(best1[rt], dv[j]);
                    bid[rt]   = gt ? (c_base + j) : bid[rt];
                    best2[rt] = nb2;
                }
            }
        }

        // wait only the 8 DMA issues (stores newer in queue keep flying)
        asm volatile("s_waitcnt vmcnt(16)" ::: "memory");
        __builtin_amdgcn_s_barrier();
        asm volatile("" ::: "memory");
    }

    // ---- reduce top-2 across the 4 l4-lanes sharing each x-row (xor 16, 32) ----
    #pragma unroll
    for (int rt = 0; rt < 2; ++rt) {
        float v1 = best1[rt], v2 = best2[rt];
        int   id = bid[rt];
        #pragma unroll
        for (int off = 16; off <= 32; off <<= 1) {
            float ov = __shfl_xor(v1, off, 64);
            int   oi = __shfl_xor(id, off, 64);
            float ow = __shfl_xor(v2, off, 64);
            float lo = (ov > v1) ? v1 : ov;   // loser of the two firsts
            if (ov > v1 || (ov == v1 && oi < id)) { v1 = ov; id = oi; }
            v2 = fmaxf(fmaxf(v2, ow), lo);
        }
        const int row = n0 + wv*32 + rt*16 + l15;
        const float* er = eh_ + (size_t)id*DD + l4*16;
        float*       qr = out_q + ((size_t)h*NROW + row)*DD + l4*16;
        #pragma unroll
        for (int i = 0; i < 4; ++i)
            *(float4*)(qr + i*4) = *(const float4*)(er + i*4);
        if (l4 == 0) {
            out_i [(size_t)h*NROW + row] = (float)id;
            margin[(size_t)h*NROW + row] = v1 - v2;
            out_oh[((size_t)h*NROW + row)*CC + id] = 1.0f;
        }
    }
}

// ------------- kernel 2b: exact-argmax fixup for near-tie rows (patches i/q/oh) -------------
__global__ __launch_bounds__(64)
void fixup_kernel(const float* __restrict__ x, const float* __restrict__ embed,
                  const float* __restrict__ fsq, const float* __restrict__ esq,
                  const float* __restrict__ margin, float* __restrict__ out_i,
                  float* __restrict__ out_q, float* __restrict__ out_oh) {
    const int blk  = blockIdx.x;
    const int h    = blk >> 8;            // NROW/64 = 256 blocks per head
    const int r0   = (blk & 255) * 64;
    const int lane = threadIdx.x;

    float m = margin[(size_t)h*NROW + r0 + lane];
    unsigned long long mask = __ballot(m < TAU);

    while (mask) {
        int t = __ffsll(mask) - 1;
        mask &= mask - 1;
        const int row = r0 + t;

        const int old = (int)out_i[(size_t)h*NROW + row];

        const float* xr  = x + ((size_t)h*NROW + row)*DD;
        const float  fsv = fsq[(size_t)h*NROW + row];

        float best = -3.4e38f;
        int   bidx = 0;
        for (int g = 0; g < 16; ++g) {
            const int c = g*64 + lane;
            const float* er = embed + ((size_t)h*CC + c)*DD;
            float acc = 0.f;
            #pragma unroll
            for (int k4 = 0; k4 < 16; ++k4) {
                float4 xv = *(const float4*)(xr + k4*4);
                float4 ev = *(const float4*)(er + k4*4);
                acc = fmaf(xv.x, ev.x, acc); acc = fmaf(xv.y, ev.y, acc);
                acc = fmaf(xv.z, ev.z, acc); acc = fmaf(xv.w, ev.w, acc);
            }
            float dv = fmaf(2.f, acc, -(fsv + esq[h*CC + c]));
            if (dv > best) { best = dv; bidx = c; }
        }
        #pragma unroll
        for (int off = 32; off >= 1; off >>= 1) {
            float ov = __shfl_xor(best, off, 64);
            int   oi = __shfl_xor(bidx, off, 64);
            if (ov > best || (ov == best && oi < bidx)) { best = ov; bidx = oi; }
        }
        if (lane == 0) {
            out_i[(size_t)h*NROW + row] = (float)bidx;
            out_oh[((size_t)h*NROW + row)*CC + old]  = 0.0f;
            out_oh[((size_t)h*NROW + row)*CC + bidx] = 1.0f;
        }
        if (lane < 16) {
            *(float4*)(out_q + ((size_t)h*NROW + row)*DD + lane*4) =
                *(const float4*)(embed + ((size_t)h*CC + bidx)*DD + lane*4);
        }
    }
}

// ------------- kernel 3: deterministic EMA updates -------------
__global__ __launch_bounds__(64)
void ema_kernel(const float* __restrict__ x, const float* __restrict__ embed_avg,
                const float* __restrict__ cluster_size, const float* __restrict__ ind_f,
                float* __restrict__ out_cs, float* __restrict__ out_ea,
                float* __restrict__ out_norm) {
    const int h    = blockIdx.y;
    const int c    = blockIdx.x;
    const int lane = threadIdx.x;

    const float* cs_h = cluster_size + h*CC;
    float s = 0.f;
    #pragma unroll
    for (int i = 0; i < CC/64; ++i) s += cs_h[lane + i*64];
    #pragma unroll
    for (int off = 32; off >= 1; off >>= 1) s += __shfl_xor(s, off, 64);

    const float* xh   = x     + (size_t)h * NROW * DD;
    const float* indh = ind_f + (size_t)h * NROW;

    float sum_d = 0.f;
    int   cnt   = 0;
    for (int chunk = 0; chunk < NROW/64; ++chunk) {
        int myidx = (int)indh[chunk*64 + lane];
        unsigned long long m = __ballot(myidx == c);
        while (m) {
            int t = __ffsll(m) - 1;
            m &= m - 1;
            int n = chunk*64 + t;
            sum_d += xh[(size_t)n*DD + lane];
            cnt++;
        }
    }

    float csn  = cs_h[c]*DECAY + (float)cnt*(1.f - DECAY);
    float ea   = embed_avg[((size_t)h*CC + c)*DD + lane]*DECAY + sum_d*(1.f - DECAY);
    float ntot = s*DECAY + (1.f - DECAY)*(float)NROW;
    float css  = (csn + EPS) / (ntot + (float)CC*EPS) * ntot;

    out_ea  [((size_t)h*CC + c)*DD + lane] = ea;
    out_norm[((size_t)h*CC + c)*DD + lane] = ea / css;
    if (lane == 0) out_cs[h*CC + c] = csn;
}

extern "C" void kernel_launch(void* const* d_in, const int* in_sizes, int n_in,
                              void* d_out, int out_size, void* d_ws, size_t ws_size,
                              hipStream_t stream) {
    const float* x            = (const float*)d_in[0];
    const float* embed        = (const float*)d_in[1];
    const float* embed_avg    = (const float*)d_in[2];
    const float* cluster_size = (const float*)d_in[3];

    float* out = (float*)d_out;
    float* fsq    = (float*)d_ws;
    float* esq    = fsq    + (size_t)HN * NROW;
    float* margin = esq    + (size_t)HN * CC;
    _Float16* esplit = (_Float16*)(margin + (size_t)HN * NROW);   // 2 MB, 16B-aligned

    float* out_q    = out;
    float* out_i    = out_q    + (size_t)HN * NROW * DD;
    float* out_oh   = out_i    + (size_t)HN * NROW;
    float* out_d    = out_oh   + (size_t)HN * NROW * CC;
    float* out_norm = out_d    + (size_t)HN * NROW * CC;
    float* out_ea   = out_norm + (size_t)HN * CC * DD;
    float* out_cs   = out_ea   + (size_t)HN * CC * DD;

    // zero the one-hot output with a pure-BW fill (stream-ordered before k2)
    hipMemsetAsync(out_oh, 0, (size_t)HN * NROW * CC * sizeof(float), stream);

    {
        int total = HN*NROW + HN*CC;
        sumsq_kernel<<<(total + 255)/256, 256, 0, stream>>>(x, embed, fsq, esq);
    }
    {
        presplit_kernel<<<(HN*CC*8)/256, 256, 0, stream>>>(embed, esplit);
    }
    {
        dim3 g(NROW/128, HN);
        dist_mfma_kernel<<<g, 256, 0, stream>>>(x, esplit, embed, fsq, esq,
                                                out_i, margin, out_q, out_oh, out_d);
    }
    {
        fixup_kernel<<<HN * (NROW/64), 64, 0, stream>>>(x, embed, fsq, esq, margin,
                                                        out_i, out_q, out_oh);
    }
    {
        dim3 g(CC, HN);
        ema_kernel<<<g, 64, 0, stream>>>(x, embed_avg, cluster_size, out_i,
                                         out_cs, out_ea, out_norm);
    }
}

// Round 13
// 636.543 us; speedup vs baseline: 1.0516x; 1.0516x over previous
//
#include <hip/hip_runtime.h>

#define DECAY 0.8f
#define EPS   1e-5f
#define HN    8
#define BB    8
#define NSEQ  2048
#define DD    64
#define CC    1024
#define NROW  (BB*NSEQ)   /* 16384 rows per head */
#define TAU   0.02f       /* margin threshold; split err bound ~1e-4 -> 100x safety */

typedef _Float16 f16x8 __attribute__((ext_vector_type(8)));
typedef float    f32x4 __attribute__((ext_vector_type(4)));
typedef float    vf4   __attribute__((ext_vector_type(4)));

#define MFMA16(a,b,c) __builtin_amdgcn_mfma_f32_16x16x32_f16(a, b, c, 0, 0, 0)

#define GLL16(gsrc, ldst) \
  __builtin_amdgcn_global_load_lds((const __attribute__((address_space(1))) void*)(gsrc), \
                                   (__attribute__((address_space(3))) void*)(ldst), 16, 0, 0)

// ---------------- kernel 1: row sum-of-squares for x and embed ----------------
__global__ void sumsq_kernel(const float* __restrict__ x, const float* __restrict__ embed,
                             float* __restrict__ fsq, float* __restrict__ esq) {
    int tid = blockIdx.x * blockDim.x + threadIdx.x;
    const int totalF = HN * NROW;
    const int totalE = HN * CC;
    if (tid < totalF) {
        const float4* src = (const float4*)(x + (size_t)tid * DD);
        float s = 0.f;
        #pragma unroll
        for (int i = 0; i < DD/4; ++i) {
            float4 v = src[i];
            s = fmaf(v.x, v.x, s); s = fmaf(v.y, v.y, s);
            s = fmaf(v.z, v.z, s); s = fmaf(v.w, v.w, s);
        }
        fsq[tid] = s;
    } else if (tid < totalF + totalE) {
        int t = tid - totalF;
        const float4* src = (const float4*)(embed + (size_t)t * DD);
        float s = 0.f;
        #pragma unroll
        for (int i = 0; i < DD/4; ++i) {
            float4 v = src[i];
            s = fmaf(v.x, v.x, s); s = fmaf(v.y, v.y, s);
            s = fmaf(v.z, v.z, s); s = fmaf(v.w, v.w, s);
        }
        esq[t] = s;
    }
}

// swizzled byte offset for [col][k] f16 plane (row stride 128 B)
__device__ __forceinline__ int lds_off(int col, int k) {
    return (col * 128 + k * 2) ^ ((col & 7) << 4);
}

// ---------------- kernel 1b: pre-split embed into swizzled f16 hi/lo planes ----------------
__global__ __launch_bounds__(256)
void presplit_kernel(const float* __restrict__ embed, _Float16* __restrict__ esplit) {
    const int t    = blockIdx.x * 256 + threadIdx.x;   // 65536 threads
    const int kg   = (t & 7) * 8;                      // k group of 8
    const int code = t >> 3;                           // h*1024 + c
    const int h    = code >> 10;
    const int c    = code & 1023;
    const int chunk = c >> 7;
    const int col   = c & 127;

    const float* s = embed + (size_t)code * DD + kg;
    float4 v0 = *(const float4*)s;
    float4 v1 = *(const float4*)(s + 4);
    float f0 = v0.x, f1 = v0.y, f2 = v0.z, f3 = v0.w;
    float f4 = v1.x, f5 = v1.y, f6 = v1.z, f7 = v1.w;

    f16x8 hi, lo;
    hi[0] = (_Float16)f0; lo[0] = (_Float16)(f0 - (float)hi[0]);
    hi[1] = (_Float16)f1; lo[1] = (_Float16)(f1 - (float)hi[1]);
    hi[2] = (_Float16)f2; lo[2] = (_Float16)(f2 - (float)hi[2]);
    hi[3] = (_Float16)f3; lo[3] = (_Float16)(f3 - (float)hi[3]);
    hi[4] = (_Float16)f4; lo[4] = (_Float16)(f4 - (float)hi[4]);
    hi[5] = (_Float16)f5; lo[5] = (_Float16)(f5 - (float)hi[5]);
    hi[6] = (_Float16)f6; lo[6] = (_Float16)(f6 - (float)hi[6]);
    hi[7] = (_Float16)f7; lo[7] = (_Float16)(f7 - (float)hi[7]);

    char* base = (char*)esplit + ((size_t)(h*8 + chunk)) * 32768;
    const int off = lds_off(col, kg);
    *(f16x8*)(base + off)         = hi;
    *(f16x8*)(base + 16384 + off) = lo;
}

// ------------- kernel 2: MFMA dist + LDS-transposed full-line stores + argmax/margin/q/oh -------------
__global__ __launch_bounds__(256, 2)
void dist_mfma_kernel(const float* __restrict__ x, const _Float16* __restrict__ esplit,
                      const float* __restrict__ embed,
                      const float* __restrict__ fsq, const float* __restrict__ esq,
                      float* __restrict__ out_i, float* __restrict__ margin,
                      float* __restrict__ out_q, float* __restrict__ out_oh,
                      float* __restrict__ out_d) {
    __shared__ _Float16 eb[2][16384];   // [buf][hi 8192 | lo 8192], 64 KiB
    __shared__ vf4 tsb4[4][32 * 8];     // per-wave 32x32 f32 transpose tile, 16 KiB

    const int h   = blockIdx.y;
    const int n0  = blockIdx.x * 128;
    const int tid = threadIdx.x;
    const int wv  = tid >> 6;       // wave 0..3 -> x rows wv*32..wv*32+31
    const int l   = tid & 63;
    const int l15 = l & 15;         // x-row within 16
    const int l4  = l >> 4;         // code sub-group

    const float* xh_   = x     + (size_t)h * NROW * DD;
    const float* eh_   = embed + (size_t)h * CC   * DD;
    const float* esq_h = esq   + h * CC;
    const _Float16* es_h = esplit + (size_t)h * 8 * 16384;

    // ---- stage chunk 0 into buf 0 (async DMA) ----
    #pragma unroll
    for (int i = 0; i < 8; ++i) {
        const int o = (i*4 + wv) * 512;              // f16 offset, wave-uniform
        GLL16(es_h + o + l*8, &eb[0][o]);
    }

    // ---- X fragments (B operand): x-row = n0+wv*32+rt*16+l15, k = ks*32+l4*8+j ----
    f16x8 Xh[2][2], Xl[2][2];
    #pragma unroll
    for (int rt = 0; rt < 2; ++rt)
        #pragma unroll
        for (int ks = 0; ks < 2; ++ks) {
            const float* src = xh_ + (size_t)(n0 + wv*32 + rt*16 + l15) * DD + ks*32 + l4*8;
            float4 v0 = *(const float4*)src;
            float4 v1 = *(const float4*)(src + 4);
            f16x8 hh, ll;
            hh[0] = (_Float16)v0.x; ll[0] = (_Float16)(v0.x - (float)hh[0]);
            hh[1] = (_Float16)v0.y; ll[1] = (_Float16)(v0.y - (float)hh[1]);
            hh[2] = (_Float16)v0.z; ll[2] = (_Float16)(v0.z - (float)hh[2]);
            hh[3] = (_Float16)v0.w; ll[3] = (_Float16)(v0.w - (float)hh[3]);
            hh[4] = (_Float16)v1.x; ll[4] = (_Float16)(v1.x - (float)hh[4]);
            hh[5] = (_Float16)v1.y; ll[5] = (_Float16)(v1.y - (float)hh[5]);
            hh[6] = (_Float16)v1.z; ll[6] = (_Float16)(v1.z - (float)hh[6]);
            hh[7] = (_Float16)v1.w; ll[7] = (_Float16)(v1.w - (float)hh[7]);
            Xh[rt][ks] = hh; Xl[rt][ks] = ll;
        }

    float fs[2];
    #pragma unroll
    for (int rt = 0; rt < 2; ++rt)
        fs[rt] = fsq[h*NROW + n0 + wv*32 + rt*16 + l15];

    asm volatile("s_waitcnt vmcnt(0)" ::: "memory");
    __builtin_amdgcn_s_barrier();
    asm volatile("" ::: "memory");

    float best1[2], best2[2];
    int   bid[2];
    #pragma unroll
    for (int rt = 0; rt < 2; ++rt) { best1[rt] = -3.4e38f; best2[rt] = -3.4e38f; bid[rt] = 0; }

    #pragma unroll 1
    for (int ci = 0; ci < 8; ++ci) {
        const int c0 = ci * 128;
        const int b  = ci & 1;

        // issue next chunk's DMA first (oldest in vmcnt queue)
        if (ci < 7) {
            const _Float16* src = es_h + (size_t)(ci + 1) * 16384;
            #pragma unroll
            for (int i = 0; i < 8; ++i) {
                const int o = (i*4 + wv) * 512;
                GLL16(src + o + l*8, &eb[b^1][o]);
            }
        }

        const _Float16* ph = &eb[b][0];
        const _Float16* pl = &eb[b][8192];

        // 4 column-pairs of 2 ct each -> 32x32 f32 tile -> full-line stores
        #pragma unroll
        for (int t = 0; t < 4; ++t) {
            #pragma unroll
            for (int u = 0; u < 2; ++u) {
                const int ct  = t*2 + u;
                const int col = ct*16 + l15;   // embed code for this lane's A-frag
                f16x8 Eh0 = *(const f16x8*)((const char*)ph + lds_off(col, 0  + l4*8));
                f16x8 Eh1 = *(const f16x8*)((const char*)ph + lds_off(col, 32 + l4*8));
                f16x8 El0 = *(const f16x8*)((const char*)pl + lds_off(col, 0  + l4*8));
                f16x8 El1 = *(const f16x8*)((const char*)pl + lds_off(col, 32 + l4*8));

                f32x4 a0 = {0.f, 0.f, 0.f, 0.f};
                f32x4 a1 = {0.f, 0.f, 0.f, 0.f};
                a0 = MFMA16(Eh0, Xh[0][0], a0); a1 = MFMA16(Eh0, Xh[1][0], a1);
                a0 = MFMA16(Eh1, Xh[0][1], a0); a1 = MFMA16(Eh1, Xh[1][1], a1);
                a0 = MFMA16(Eh0, Xl[0][0], a0); a1 = MFMA16(Eh0, Xl[1][0], a1);
                a0 = MFMA16(Eh1, Xl[0][1], a0); a1 = MFMA16(Eh1, Xl[1][1], a1);
                a0 = MFMA16(El0, Xh[0][0], a0); a1 = MFMA16(El0, Xh[1][0], a1);
                a0 = MFMA16(El1, Xh[0][1], a0); a1 = MFMA16(El1, Xh[1][1], a1);

                const int c_base = c0 + ct*16 + l4*4;   // 4 consecutive codes
                float eq[4];
                *(float4*)&eq[0] = *(const float4*)(esq_h + c_base);

                #pragma unroll
                for (int rt = 0; rt < 2; ++rt) {
                    const f32x4 acc = rt ? a1 : a0;
                    float dv[4];
                    #pragma unroll
                    for (int j = 0; j < 4; ++j)
                        dv[j] = fmaf(2.f, acc[j], -(fs[rt] + eq[j]));

                    // stage into per-wave transpose tile (swizzled, no barrier needed)
                    {
                        const int R  = rt*16 + l15;          // tile row 0..31
                        const int q  = u*4 + l4;             // col-quad 0..7 within 32 cols
                        const int pq = q ^ (R & 7);
                        vf4 d4 = {dv[0], dv[1], dv[2], dv[3]};
                        tsb4[wv][R*8 + pq] = d4;
                    }

                    #pragma unroll
                    for (int j = 0; j < 4; ++j) {
                        float nb2 = fmaxf(best2[rt], fminf(dv[j], best1[rt]));
                        bool  gt  = dv[j] > best1[rt];
                        best1[rt] = fmaxf(best1[rt], dv[j]);
                        bid[rt]   = gt ? (c_base + j) : bid[rt];
                        best2[rt] = nb2;
                    }
                }
            }

            // read back row-major and store full 128B lines (8 lanes x 16B per row)
            #pragma unroll
            for (int i = 0; i < 4; ++i) {
                const int R  = i*8 + (l >> 3);
                const int q  = l & 7;
                const int pq = q ^ (R & 7);
                vf4 v = tsb4[wv][R*8 + pq];
                const int row = n0 + wv*32 + R;
                *(vf4*)(out_d + ((size_t)h*NROW + row)*CC + c0 + t*32 + q*4) = v;
            }
        }

        // wait only the 8 DMA issues; this chunk's 16 stores stay in flight
        asm volatile("s_waitcnt vmcnt(16)" ::: "memory");
        __builtin_amdgcn_s_barrier();
        asm volatile("" ::: "memory");
    }

    // ---- reduce top-2 across the 4 l4-lanes sharing each x-row (xor 16, 32) ----
    #pragma unroll
    for (int rt = 0; rt < 2; ++rt) {
        float v1 = best1[rt], v2 = best2[rt];
        int   id = bid[rt];
        #pragma unroll
        for (int off = 16; off <= 32; off <<= 1) {
            float ov = __shfl_xor(v1, off, 64);
            int   oi = __shfl_xor(id, off, 64);
            float ow = __shfl_xor(v2, off, 64);
            float lo = (ov > v1) ? v1 : ov;   // loser of the two firsts
            if (ov > v1 || (ov == v1 && oi < id)) { v1 = ov; id = oi; }
            v2 = fmaxf(fmaxf(v2, ow), lo);
        }
        const int row = n0 + wv*32 + rt*16 + l15;
        const float* er = eh_ + (size_t)id*DD + l4*16;
        float*       qr = out_q + ((size_t)h*NROW + row)*DD + l4*16;
        #pragma unroll
        for (int i = 0; i < 4; ++i)
            *(float4*)(qr + i*4) = *(const float4*)(er + i*4);
        if (l4 == 0) {
            out_i [(size_t)h*NROW + row] = (float)id;
            margin[(size_t)h*NROW + row] = v1 - v2;
            out_oh[((size_t)h*NROW + row)*CC + id] = 1.0f;
        }
    }
}

// ------------- kernel 2b: exact-argmax fixup for near-tie rows (patches i/q/oh) -------------
__global__ __launch_bounds__(64)
void fixup_kernel(const float* __restrict__ x, const float* __restrict__ embed,
                  const float* __restrict__ fsq, const float* __restrict__ esq,
                  const float* __restrict__ margin, float* __restrict__ out_i,
                  float* __restrict__ out_q, float* __restrict__ out_oh) {
    const int blk  = blockIdx.x;
    const int h    = blk >> 8;            // NROW/64 = 256 blocks per head
    const int r0   = (blk & 255) * 64;
    const int lane = threadIdx.x;

    float m = margin[(size_t)h*NROW + r0 + lane];
    unsigned long long mask = __ballot(m < TAU);

    while (mask) {
        int t = __ffsll(mask) - 1;
        mask &= mask - 1;
        const int row = r0 + t;

        const int old = (int)out_i[(size_t)h*NROW + row];

        const float* xr  = x + ((size_t)h*NROW + row)*DD;
        const float  fsv = fsq[(size_t)h*NROW + row];

        float best = -3.4e38f;
        int   bidx = 0;
        for (int g = 0; g < 16; ++g) {
            const int c = g*64 + lane;
            const float* er = embed + ((size_t)h*CC + c)*DD;
            float acc = 0.f;
            #pragma unroll
            for (int k4 = 0; k4 < 16; ++k4) {
                float4 xv = *(const float4*)(xr + k4*4);
                float4 ev = *(const float4*)(er + k4*4);
                acc = fmaf(xv.x, ev.x, acc); acc = fmaf(xv.y, ev.y, acc);
                acc = fmaf(xv.z, ev.z, acc); acc = fmaf(xv.w, ev.w, acc);
            }
            float dv = fmaf(2.f, acc, -(fsv + esq[h*CC + c]));
            if (dv > best) { best = dv; bidx = c; }
        }
        #pragma unroll
        for (int off = 32; off >= 1; off >>= 1) {
            float ov = __shfl_xor(best, off, 64);
            int   oi = __shfl_xor(bidx, off, 64);
            if (ov > best || (ov == best && oi < bidx)) { best = ov; bidx = oi; }
        }
        if (lane == 0) {
            out_i[(size_t)h*NROW + row] = (float)bidx;
            out_oh[((size_t)h*NROW + row)*CC + old]  = 0.0f;
            out_oh[((size_t)h*NROW + row)*CC + bidx] = 1.0f;
        }
        if (lane < 16) {
            *(float4*)(out_q + ((size_t)h*NROW + row)*DD + lane*4) =
                *(const float4*)(embed + ((size_t)h*CC + bidx)*DD + lane*4);
        }
    }
}

// ------------- kernel 3: deterministic EMA updates -------------
__global__ __launch_bounds__(64)
void ema_kernel(const float* __restrict__ x, const float* __restrict__ embed_avg,
                const float* __restrict__ cluster_size, const float* __restrict__ ind_f,
                float* __restrict__ out_cs, float* __restrict__ out_ea,
                float* __restrict__ out_norm) {
    const int h    = blockIdx.y;
    const int c    = blockIdx.x;
    const int lane = threadIdx.x;

    const float* cs_h = cluster_size + h*CC;
    float s = 0.f;
    #pragma unroll
    for (int i = 0; i < CC/64; ++i) s += cs_h[lane + i*64];
    #pragma unroll
    for (int off = 32; off >= 1; off >>= 1) s += __shfl_xor(s, off, 64);

    const float* xh   = x     + (size_t)h * NROW * DD;
    const float* indh = ind_f + (size_t)h * NROW;

    float sum_d = 0.f;
    int   cnt   = 0;
    for (int chunk = 0; chunk < NROW/64; ++chunk) {
        int myidx = (int)indh[chunk*64 + lane];
        unsigned long long m = __ballot(myidx == c);
        while (m) {
            int t = __ffsll(m) - 1;
            m &= m - 1;
            int n = chunk*64 + t;
            sum_d += xh[(size_t)n*DD + lane];
            cnt++;
        }
    }

    float csn  = cs_h[c]*DECAY + (float)cnt*(1.f - DECAY);
    float ea   = embed_avg[((size_t)h*CC + c)*DD + lane]*DECAY + sum_d*(1.f - DECAY);
    float ntot = s*DECAY + (1.f - DECAY)*(float)NROW;
    float css  = (csn + EPS) / (ntot + (float)CC*EPS) * ntot;

    out_ea  [((size_t)h*CC + c)*DD + lane] = ea;
    out_norm[((size_t)h*CC + c)*DD + lane] = ea / css;
    if (lane == 0) out_cs[h*CC + c] = csn;
}

extern "C" void kernel_launch(void* const* d_in, const int* in_sizes, int n_in,
                              void* d_out, int out_size, void* d_ws, size_t ws_size,
                              hipStream_t stream) {
    const float* x            = (const float*)d_in[0];
    const float* embed        = (const float*)d_in[1];
    const float* embed_avg    = (const float*)d_in[2];
    const float* cluster_size = (const float*)d_in[3];

    float* out = (float*)d_out;
    float* fsq    = (float*)d_ws;
    float* esq    = fsq    + (size_t)HN * NROW;
    float* margin = esq    + (size_t)HN * CC;
    _Float16* esplit = (_Float16*)(margin + (size_t)HN * NROW);   // 2 MB, 16B-aligned

    float* out_q    = out;
    float* out_i    = out_q    + (size_t)HN * NROW * DD;
    float* out_oh   = out_i    + (size_t)HN * NROW;
    float* out_d    = out_oh   + (size_t)HN * NROW * CC;
    float* out_norm = out_d    + (size_t)HN * NROW * CC;
    float* out_ea   = out_norm + (size_t)HN * CC * DD;
    float* out_cs   = out_ea   + (size_t)HN * CC * DD;

    // zero the one-hot output with a pure-BW fill (stream-ordered before k2)
    hipMemsetAsync(out_oh, 0, (size_t)HN * NROW * CC * sizeof(float), stream);

    {
        int total = HN*NROW + HN*CC;
        sumsq_kernel<<<(total + 255)/256, 256, 0, stream>>>(x, embed, fsq, esq);
    }
    {
        presplit_kernel<<<(HN*CC*8)/256, 256, 0, stream>>>(embed, esplit);
    }
    {
        dim3 g(NROW/128, HN);
        dist_mfma_kernel<<<g, 256, 0, stream>>>(x, esplit, embed, fsq, esq,
                                                out_i, margin, out_q, out_oh, out_d);
    }
    {
        fixup_kernel<<<HN * (NROW/64), 64, 0, stream>>>(x, embed, fsq, esq, margin,
                                                        out_i, out_q, out_oh);
    }
    {
        dim3 g(CC, HN);
        ema_kernel<<<g, 64, 0, stream>>>(x, embed_avg, cluster_size, out_i,
                                         out_cs, out_ea, out_norm);
    }
}